// Round 1
// baseline (473.150 us; speedup 1.0000x reference)
//
#include <hip/hip_runtime.h>

#define NN 8192
#define NFEAT 512
#define NHID 128
#define NCLASS 16
#define CAP 128

// ---------------------------------------------------------------------------
// Kernel 1: single pass over dense adj. Per row: compact nonzero column
// indices into cols[row][0..cnt), write rowcnt, and dinv = rsqrt(nnz + 1)
// (the +1 is the GCN self-loop; if adj[i][i]==1 it also appears in the list,
// which matches a_hat = adj + I exactly).
// ---------------------------------------------------------------------------
__global__ __launch_bounds__(256) void k1_build(const float* __restrict__ adj,
                                                int* __restrict__ rowcnt,
                                                int* __restrict__ cols,
                                                float* __restrict__ dinv) {
  int row = blockIdx.x;
  __shared__ int cnt;
  if (threadIdx.x == 0) cnt = 0;
  __syncthreads();
  const float4* arow = (const float4*)(adj + (size_t)row * NN);
  int* crow = cols + (size_t)row * CAP;
  for (int i = threadIdx.x; i < NN / 4; i += 256) {
    float4 v = arow[i];
    int j0 = i * 4;
    if (v.x != 0.0f) { int s = atomicAdd(&cnt, 1); if (s < CAP) crow[s] = j0; }
    if (v.y != 0.0f) { int s = atomicAdd(&cnt, 1); if (s < CAP) crow[s] = j0 + 1; }
    if (v.z != 0.0f) { int s = atomicAdd(&cnt, 1); if (s < CAP) crow[s] = j0 + 2; }
    if (v.w != 0.0f) { int s = atomicAdd(&cnt, 1); if (s < CAP) crow[s] = j0 + 3; }
  }
  __syncthreads();
  if (threadIdx.x == 0) {
    rowcnt[row] = min(cnt, CAP);
    dinv[row] = rsqrtf((float)cnt + 1.0f);
  }
}

// ---------------------------------------------------------------------------
// Kernel 2: xw = x @ W1.  [8192,512] @ [512,128], f32.
// 256 thr/block; thread (p = tid&63, g = tid>>6) computes 4 rows x 2 cols.
// Block covers 16 rows x 128 cols. x reads are wave-uniform (L1/scalar
// broadcast); W1 reads are coalesced and L2-resident (256 KB).
// ---------------------------------------------------------------------------
__global__ __launch_bounds__(256) void k2_gemm1(const float* __restrict__ x,
                                                const float* __restrict__ W1,
                                                float* __restrict__ xw) {
  int p = threadIdx.x & 63;
  int g = threadIdx.x >> 6;                 // 0..3
  int rbase = blockIdx.x * 16 + g * 4;
  const float* xr0 = x + (size_t)rbase * NFEAT;
  float acc[4][2] = {};
  for (int k = 0; k < NFEAT; k += 4) {
    float4 xv[4];
#pragma unroll
    for (int r = 0; r < 4; ++r)
      xv[r] = *(const float4*)(xr0 + (size_t)r * NFEAT + k);
#pragma unroll
    for (int t = 0; t < 4; ++t) {
      float w0 = W1[(size_t)(k + t) * NHID + p];
      float w1 = W1[(size_t)(k + t) * NHID + p + 64];
#pragma unroll
      for (int r = 0; r < 4; ++r) {
        float xe = (t == 0) ? xv[r].x : (t == 1) ? xv[r].y
                 : (t == 2) ? xv[r].z : xv[r].w;
        acc[r][0] = fmaf(xe, w0, acc[r][0]);
        acc[r][1] = fmaf(xe, w1, acc[r][1]);
      }
    }
  }
#pragma unroll
  for (int r = 0; r < 4; ++r) {
    xw[(size_t)(rbase + r) * NHID + p]      = acc[r][0];
    xw[(size_t)(rbase + r) * NHID + p + 64] = acc[r][1];
  }
}

// ---------------------------------------------------------------------------
// Kernel 3: h = relu(dinv_i * (sum_{j in nbr} dinv_j*xw_j + dinv_i*xw_i) + b1)
// One block (128 thr, one per hidden col) per row. Neighbor rows of xw are
// 512 B coalesced gathers; xw is 4 MB -> L2/L3 resident.
// ---------------------------------------------------------------------------
__global__ __launch_bounds__(128) void k3_spmm1(const float* __restrict__ xw,
                                                const int* __restrict__ rowcnt,
                                                const int* __restrict__ cols,
                                                const float* __restrict__ dinv,
                                                const float* __restrict__ b1,
                                                float* __restrict__ h) {
  int row = blockIdx.x;
  int c = threadIdx.x;
  int cnt = rowcnt[row];
  const int* crow = cols + (size_t)row * CAP;
  float di = dinv[row];
  float acc = di * xw[(size_t)row * NHID + c];   // identity self-loop term
  for (int e = 0; e < cnt; ++e) {
    int j = crow[e];
    acc = fmaf(dinv[j], xw[(size_t)j * NHID + c], acc);
  }
  float v = fmaf(di, acc, b1[c]);
  h[(size_t)row * NHID + c] = fmaxf(v, 0.0f);
}

// ---------------------------------------------------------------------------
// Kernel 4: hw = h @ W2.  [8192,128] @ [128,16]. Thread per (row, class).
// ---------------------------------------------------------------------------
__global__ __launch_bounds__(256) void k4_gemm2(const float* __restrict__ h,
                                                const float* __restrict__ W2,
                                                float* __restrict__ hw) {
  int gid = blockIdx.x * 256 + threadIdx.x;
  int row = gid >> 4;
  int c = gid & 15;
  const float* hr = h + (size_t)row * NHID;
  float acc = 0.0f;
  for (int k = 0; k < NHID; k += 4) {
    float4 hv = *(const float4*)(hr + k);
    acc = fmaf(hv.x, W2[(size_t)(k + 0) * NCLASS + c], acc);
    acc = fmaf(hv.y, W2[(size_t)(k + 1) * NCLASS + c], acc);
    acc = fmaf(hv.z, W2[(size_t)(k + 2) * NCLASS + c], acc);
    acc = fmaf(hv.w, W2[(size_t)(k + 3) * NCLASS + c], acc);
  }
  hw[(size_t)row * NCLASS + c] = acc;
}

// ---------------------------------------------------------------------------
// Kernel 5: out = log_softmax(a_norm @ hw + b2). Thread per (row, class);
// 16-lane-group shuffle reductions for max / sum-exp.
// ---------------------------------------------------------------------------
__global__ __launch_bounds__(256) void k5_out(const float* __restrict__ hw,
                                              const int* __restrict__ rowcnt,
                                              const int* __restrict__ cols,
                                              const float* __restrict__ dinv,
                                              const float* __restrict__ b2,
                                              float* __restrict__ out) {
  int gid = blockIdx.x * 256 + threadIdx.x;
  int row = gid >> 4;
  int c = gid & 15;
  int cnt = rowcnt[row];
  const int* crow = cols + (size_t)row * CAP;
  float di = dinv[row];
  float acc = di * hw[(size_t)row * NCLASS + c];
  for (int e = 0; e < cnt; ++e) {
    int j = crow[e];
    acc = fmaf(dinv[j], hw[(size_t)j * NCLASS + c], acc);
  }
  float v = fmaf(di, acc, b2[c]);
  // log_softmax across the 16 lanes of this row-group
  float m = v;
#pragma unroll
  for (int o = 8; o >= 1; o >>= 1) m = fmaxf(m, __shfl_xor(m, o, 16));
  float ex = __expf(v - m);
  float s = ex;
#pragma unroll
  for (int o = 8; o >= 1; o >>= 1) s += __shfl_xor(s, o, 16);
  out[(size_t)row * NCLASS + c] = v - m - logf(s);
}

// ---------------------------------------------------------------------------

extern "C" void kernel_launch(void* const* d_in, const int* in_sizes, int n_in,
                              void* d_out, int out_size, void* d_ws, size_t ws_size,
                              hipStream_t stream) {
  const float* x   = (const float*)d_in[0];
  const float* adj = (const float*)d_in[1];
  const float* W1  = (const float*)d_in[2];
  const float* b1  = (const float*)d_in[3];
  const float* W2  = (const float*)d_in[4];
  const float* b2  = (const float*)d_in[5];
  float* out = (float*)d_out;

  char* ws = (char*)d_ws;
  float* dinv  = (float*)(ws);                               // 32 KB
  int*   rowc  = (int*)(ws + 32768);                         // 32 KB
  int*   cols  = (int*)(ws + 65536);                         // 4 MB
  float* xw    = (float*)(ws + 65536 + 4194304);             // 4 MB
  float* h     = (float*)(ws + 65536 + 8388608);             // 4 MB
  float* hw    = (float*)(ws + 65536 + 12582912);            // 512 KB

  // 1. graph build + degrees (the only full read of adj: 268 MB)
  k1_build<<<NN, 256, 0, stream>>>(adj, rowc, cols, dinv);
  // 2. xw = x @ W1
  k2_gemm1<<<NN / 16, 256, 0, stream>>>(x, W1, xw);
  // 3. h = relu(A_norm @ xw + b1)
  k3_spmm1<<<NN, 128, 0, stream>>>(xw, rowc, cols, dinv, b1, h);
  // 4. hw = h @ W2
  k4_gemm2<<<(NN * NCLASS) / 256, 256, 0, stream>>>(h, W2, hw);
  // 5. out = log_softmax(A_norm @ hw + b2)
  k5_out<<<(NN * NCLASS) / 256, 256, 0, stream>>>(hw, rowc, cols, dinv, b2, out);
}

// Round 2
// 462.301 us; speedup vs baseline: 1.0235x; 1.0235x over previous
//
#include <hip/hip_runtime.h>

#define NN 8192
#define NFEAT 512
#define NHID 128
#define NCLASS 16
#define CAP 128

// ---------------------------------------------------------------------------
// Kernel 1: single pass over dense adj (the only full 268 MB read).
// Per row: compact nonzero column indices, count, dinv = rsqrt(nnz+1).
// BW-bound floor ~42 us.
// ---------------------------------------------------------------------------
__global__ __launch_bounds__(256) void k1_build(const float* __restrict__ adj,
                                                int* __restrict__ rowcnt,
                                                int* __restrict__ cols,
                                                float* __restrict__ dinv) {
  int row = blockIdx.x;
  __shared__ int cnt;
  if (threadIdx.x == 0) cnt = 0;
  __syncthreads();
  const float4* arow = (const float4*)(adj + (size_t)row * NN);
  int* crow = cols + (size_t)row * CAP;
  for (int i = threadIdx.x; i < NN / 4; i += 256) {
    float4 v = arow[i];
    int j0 = i * 4;
    if (v.x != 0.0f) { int s = atomicAdd(&cnt, 1); if (s < CAP) crow[s] = j0; }
    if (v.y != 0.0f) { int s = atomicAdd(&cnt, 1); if (s < CAP) crow[s] = j0 + 1; }
    if (v.z != 0.0f) { int s = atomicAdd(&cnt, 1); if (s < CAP) crow[s] = j0 + 2; }
    if (v.w != 0.0f) { int s = atomicAdd(&cnt, 1); if (s < CAP) crow[s] = j0 + 3; }
  }
  __syncthreads();
  if (threadIdx.x == 0) {
    rowcnt[row] = min(cnt, CAP);
    dinv[row] = rsqrtf((float)cnt + 1.0f);
  }
}

// ---------------------------------------------------------------------------
// Kernel 2: xw = x @ W1. [8192,512]@[512,128] f32.
// 256 thr/block, 16 rows/block: p = tid&127 (col), g = tid>>7 (row half).
// Each thread: 8 rows x 1 col. Per k-step-of-4: 8 x-float4 (L1 broadcast)
// + 4 W1 scalars (coalesced, L2-hot) + 32 FMA.
// ---------------------------------------------------------------------------
__global__ __launch_bounds__(256) void k2_gemm1(const float* __restrict__ x,
                                                const float* __restrict__ W1,
                                                float* __restrict__ xw) {
  int p = threadIdx.x & 127;
  int g = threadIdx.x >> 7;                     // 0..1
  int rbase = blockIdx.x * 16 + g * 8;
  const float* xr0 = x + (size_t)rbase * NFEAT;
  float acc[8] = {};
  for (int k = 0; k < NFEAT; k += 4) {
    float4 xv[8];
#pragma unroll
    for (int r = 0; r < 8; ++r)
      xv[r] = *(const float4*)(xr0 + (size_t)r * NFEAT + k);
#pragma unroll
    for (int t = 0; t < 4; ++t) {
      float w = W1[(size_t)(k + t) * NHID + p];
#pragma unroll
      for (int r = 0; r < 8; ++r) {
        float xe = (t == 0) ? xv[r].x : (t == 1) ? xv[r].y
                 : (t == 2) ? xv[r].z : xv[r].w;
        acc[r] = fmaf(xe, w, acc[r]);
      }
    }
  }
#pragma unroll
  for (int r = 0; r < 8; ++r)
    xw[(size_t)(rbase + r) * NHID + p] = acc[r];
}

// ---------------------------------------------------------------------------
// Kernel 3 (fused): h_row = relu(A_norm @ xw + b1) computed into LDS, then
// hw_row = h_row @ W2 via per-block partial reduction. h never hits HBM.
// Block = 128 thr = one row. (j, dinv_j) prefetched to LDS in one shot
// (cnt <= 128), gather loop unrolled x4 so 4 loads are in flight.
// ---------------------------------------------------------------------------
__global__ __launch_bounds__(128) void k3_fused(const float* __restrict__ xw,
                                                const int* __restrict__ rowcnt,
                                                const int* __restrict__ cols,
                                                const float* __restrict__ dinv,
                                                const float* __restrict__ b1,
                                                const float* __restrict__ W2,
                                                float* __restrict__ hw) {
  __shared__ int   sj[CAP];
  __shared__ float sw[CAP];
  __shared__ float sh[NHID];
  __shared__ float part[128];
  int row = blockIdx.x;
  int c = threadIdx.x;
  int cnt = rowcnt[row];
  const int* crow = cols + (size_t)row * CAP;
  if (c < cnt) { int j = crow[c]; sj[c] = j; sw[c] = dinv[j]; }
  __syncthreads();
  float di = dinv[row];
  float acc = di * xw[(size_t)row * NHID + c];   // self-loop (I) term
  int e = 0;
  for (; e + 4 <= cnt; e += 4) {
    int j0 = sj[e], j1 = sj[e + 1], j2 = sj[e + 2], j3 = sj[e + 3];
    float w0 = sw[e], w1 = sw[e + 1], w2 = sw[e + 2], w3 = sw[e + 3];
    float v0 = xw[(size_t)j0 * NHID + c];
    float v1 = xw[(size_t)j1 * NHID + c];
    float v2 = xw[(size_t)j2 * NHID + c];
    float v3 = xw[(size_t)j3 * NHID + c];
    acc = fmaf(w0, v0, acc);
    acc = fmaf(w1, v1, acc);
    acc = fmaf(w2, v2, acc);
    acc = fmaf(w3, v3, acc);
  }
  for (; e < cnt; ++e) acc = fmaf(sw[e], xw[(size_t)sj[e] * NHID + c], acc);
  float h = fmaxf(fmaf(di, acc, b1[c]), 0.0f);
  sh[c] = h;
  __syncthreads();
  // h_row @ W2: thread c -> class cc = c&15, hidden segment seg = c>>4 (16 wide)
  int cc = c & 15, seg = c >> 4;
  float pacc = 0.0f;
#pragma unroll
  for (int kk = 0; kk < 16; ++kk) {
    int k = seg * 16 + kk;
    pacc = fmaf(sh[k], W2[(size_t)k * NCLASS + cc], pacc);
  }
  part[c] = pacc;
  __syncthreads();
  if (c < 16) {
    float s = 0.0f;
#pragma unroll
    for (int sg = 0; sg < 8; ++sg) s += part[c + 16 * sg];
    hw[(size_t)row * NCLASS + c] = s;
  }
}

// ---------------------------------------------------------------------------
// Kernel 4: out = log_softmax(A_norm @ hw + b2). One WAVE per row:
// lane = slot*16 + c; 4 edge-slots gather in parallel; (j,w) preloaded in
// registers (cnt<=128 -> 2 per lane) and broadcast via shfl. Slot-reduce via
// shfl_xor(16/32), then 16-wide log-softmax.
// ---------------------------------------------------------------------------
__global__ __launch_bounds__(256) void k4_out(const float* __restrict__ hw,
                                              const int* __restrict__ rowcnt,
                                              const int* __restrict__ cols,
                                              const float* __restrict__ dinv,
                                              const float* __restrict__ b2,
                                              float* __restrict__ out) {
  int lane = threadIdx.x & 63;
  int wid = threadIdx.x >> 6;
  int row = blockIdx.x * 4 + wid;
  int cnt = rowcnt[row];
  const int* crow = cols + (size_t)row * CAP;
  int jA = 0; float wA = 0.0f;
  if (lane < cnt) { jA = crow[lane]; wA = dinv[jA]; }
  int jB = 0; float wB = 0.0f;
  if (lane + 64 < cnt) { jB = crow[lane + 64]; wB = dinv[jB]; }
  int c = lane & 15, slot = lane >> 4;
  float acc = 0.0f;
  for (int e0 = 0; e0 < cnt; e0 += 4) {
    int e = e0 + slot;
    int   j1 = __shfl(jA, e & 63);
    float w1 = __shfl(wA, e & 63);
    int   j2 = __shfl(jB, (e - 64) & 63);
    float w2 = __shfl(wB, (e - 64) & 63);
    int   j = (e < 64) ? j1 : j2;
    float w = (e < 64) ? w1 : w2;
    if (e < cnt) acc = fmaf(w, hw[(size_t)j * NCLASS + c], acc);
  }
  acc += __shfl_xor(acc, 16);
  acc += __shfl_xor(acc, 32);
  float di = dinv[row];
  float self = hw[(size_t)row * NCLASS + c];
  float v = fmaf(di, acc, fmaf(di * di, self, b2[c]));
  float m = v;
#pragma unroll
  for (int o = 8; o >= 1; o >>= 1) m = fmaxf(m, __shfl_xor(m, o, 16));
  float ex = __expf(v - m);
  float s = ex;
#pragma unroll
  for (int o = 8; o >= 1; o >>= 1) s += __shfl_xor(s, o, 16);
  if (slot == 0) out[(size_t)row * NCLASS + c] = v - m - logf(s);
}

// ---------------------------------------------------------------------------

extern "C" void kernel_launch(void* const* d_in, const int* in_sizes, int n_in,
                              void* d_out, int out_size, void* d_ws, size_t ws_size,
                              hipStream_t stream) {
  const float* x   = (const float*)d_in[0];
  const float* adj = (const float*)d_in[1];
  const float* W1  = (const float*)d_in[2];
  const float* b1  = (const float*)d_in[3];
  const float* W2  = (const float*)d_in[4];
  const float* b2  = (const float*)d_in[5];
  float* out = (float*)d_out;

  char* ws = (char*)d_ws;
  float* dinv = (float*)(ws);                      // 32 KB
  int*   rowc = (int*)(ws + 32768);                // 32 KB
  int*   cols = (int*)(ws + 65536);                // 4 MB
  float* xw   = (float*)(ws + 65536 + 4194304);    // 4 MB
  float* hw   = (float*)(ws + 65536 + 8388608);    // 512 KB

  k1_build<<<NN, 256, 0, stream>>>(adj, rowc, cols, dinv);
  k2_gemm1<<<NN / 16, 256, 0, stream>>>(x, W1, xw);
  k3_fused<<<NN, 128, 0, stream>>>(xw, rowc, cols, dinv, b1, W2, hw);
  k4_out<<<NN / 4, 256, 0, stream>>>(hw, rowc, cols, dinv, b2, out);
}